// Round 8
// baseline (323.892 us; speedup 1.0000x reference)
//
#include <hip/hip_runtime.h>

#define D 512
#define D4 (D / 4)
#define MAXC 256
#define FEPS 1e-12f
#define FBIG 3.0e38f
#define DROWS 8
#define TI 32    // i-rows per k_pos block
#define TJ 64    // j-cols per k_pos block (j-split across blocks)
#define NIT 4    // i-tiles (covers class counts up to 128)
#define NJT 2    // j-tiles (covers class counts up to 128)

__device__ __forceinline__ float wave_rsum(float v) {
#pragma unroll
    for (int o = 32; o > 0; o >>= 1) v += __shfl_down(v, o);
    return v;
}

__device__ __forceinline__ float wave_rsum_all(float v) {
#pragma unroll
    for (int o = 32; o > 0; o >>= 1) v += __shfl_xor(v, o);
    return v;
}

__device__ __forceinline__ float dot4(const float4 a, const float4 b) {
    return a.x * b.x + a.y * b.y + a.z * b.z + a.w * b.w;
}

// top_k tie-break: higher value wins; equal values -> smaller global index wins
__device__ __forceinline__ bool better(float v1, int j1, float v2, int j2) {
    return (v1 > v2) || (v1 == v2 && (unsigned)j1 < (unsigned)j2);
}

__device__ __forceinline__ void ins3(float v, int j, float& t0, float& t1, float& t2,
                                     int& x0, int& x1, int& x2) {
    if (j < 0) return;
    if (better(v, j, t0, x0)) { t2 = t1; x2 = x1; t1 = t0; x1 = x0; t0 = v; x0 = j; }
    else if (better(v, j, t1, x1)) { t2 = t1; x2 = x1; t1 = v; x1 = j; }
    else if (better(v, j, t2, x2)) { t2 = v; x2 = j; }
}

// --- 1. row L2-normalize + a2[i] + fused class histogram ---
__global__ void k_normalize(const float* __restrict__ emb, const int* __restrict__ targets,
                            float* __restrict__ embn, float* __restrict__ a2,
                            int* __restrict__ ccount) {
    const int i = blockIdx.x;
    const int tid = threadIdx.x;  // 128 threads, float4 each
    __shared__ float red[2];
    const float4 x = ((const float4*)(emb + (size_t)i * D))[tid];
    float ss = x.x * x.x + x.y * x.y + x.z * x.z + x.w * x.w;
    ss = wave_rsum(ss);
    if ((tid & 63) == 0) red[tid >> 6] = ss;
    __syncthreads();
    const float tot = red[0] + red[1];
    const float inv = 1.0f / fmaxf(sqrtf(tot), FEPS);
    const float4 y = make_float4(x.x * inv, x.y * inv, x.z * inv, x.w * inv);
    ((float4*)(embn + (size_t)i * D))[tid] = y;
    float s2 = y.x * y.x + y.y * y.y + y.z * y.z + y.w * y.w;
    s2 = wave_rsum(s2);
    __syncthreads();
    if ((tid & 63) == 0) red[tid >> 6] = s2;
    __syncthreads();
    if (tid == 0) {
        a2[i] = red[0] + red[1];
        atomicAdd(&ccount[targets[i]], 1);
    }
}

// --- 2. per-class offset (in-block prefix reduce) + deterministic row lists ---
__global__ void k_build(const int* __restrict__ t, const int* __restrict__ ccount,
                        int* __restrict__ coff, int* __restrict__ clist, int n,
                        const int* __restrict__ ncls) {
    const int C = *ncls;
    const int c = blockIdx.x;  // grid = MAXC
    if (c >= C) return;
    __shared__ int pref[256];
    pref[threadIdx.x] = ((int)threadIdx.x < c) ? ccount[threadIdx.x] : 0;
    __syncthreads();
    for (int s = 128; s > 0; s >>= 1) {
        if (threadIdx.x < s) pref[threadIdx.x] += pref[threadIdx.x + s];
        __syncthreads();
    }
    int base = pref[0];
    if (threadIdx.x == 0) coff[c] = base;
    __shared__ int wtot[4];
    for (int start = 0; start < n; start += 256) {
        const int j = start + (int)threadIdx.x;
        const bool flag = (j < n) && (t[j] == c);
        const unsigned long long m = __ballot(flag);
        const int lane = threadIdx.x & 63;
        const int w = threadIdx.x >> 6;
        const int pre = __popcll(m & ((1ull << lane) - 1ull));
        if (lane == 0) wtot[w] = __popcll(m);
        __syncthreads();
        int woff = 0;
        for (int k = 0; k < w; ++k) woff += wtot[k];
        const int tot = wtot[0] + wtot[1] + wtot[2] + wtot[3];
        if (flag) clist[base + woff + pre] = j;
        base += tot;
        __syncthreads();
    }
}

// --- 3. class centers: grid (4 d-chunks x MAXC), 128 threads ---
__global__ void k_centers(const float* __restrict__ embn, const int* __restrict__ clist,
                          const int* __restrict__ coff, const int* __restrict__ ccount,
                          float* __restrict__ centers) {
    const int c = blockIdx.y;
    const int dchunk = blockIdx.x;      // 32 float4 slots each
    const int cnt = ccount[c];
    const int off = (cnt > 0) ? coff[c] : 0;
    const int tid = threadIdx.x;        // 128
    const int slot = tid & 31;
    const int rg = tid >> 5;            // 0..3
    float4 s = make_float4(0.f, 0.f, 0.f, 0.f);
    for (int mi = rg; mi < cnt; mi += 4) {
        const int j = clist[off + mi];
        const float4 e = ((const float4*)(embn + (size_t)j * D))[dchunk * 32 + slot];
        s.x += e.x; s.y += e.y; s.z += e.z; s.w += e.w;
    }
    __shared__ float4 part[4][32];
    part[rg][slot] = s;
    __syncthreads();
    if (rg == 0) {
        const float4 p0 = part[0][slot], p1 = part[1][slot], p2 = part[2][slot], p3 = part[3][slot];
        const float inv = 1.0f / fmaxf((float)cnt, 1e-6f);
        const float4 v = make_float4((p0.x + p1.x + p2.x + p3.x) * inv,
                                     (p0.y + p1.y + p2.y + p3.y) * inv,
                                     (p0.z + p1.z + p2.z + p3.z) * inv,
                                     (p0.w + p1.w + p2.w + p3.w) * inv);
        ((float4*)(centers + (size_t)c * D))[dchunk * 32 + slot] = v;
    }
}

// --- 4. d_neg_min: 8 rows per block, one thread per class (cc2 inline) ---
__global__ void k_dneg(const float* __restrict__ embn, const float* __restrict__ a2,
                       const int* __restrict__ t, const float* __restrict__ centers,
                       float* __restrict__ dneg, int n, const int* __restrict__ ncls) {
    const int C = *ncls;
    const int i0 = blockIdx.x * DROWS;
    __shared__ __align__(16) float lrow[DROWS][D];
    __shared__ float la2[DROWS];
    __shared__ int lt[DROWS];
    __shared__ float mins[DROWS][128];
#pragma unroll
    for (int r = 0; r < DROWS; ++r) {
        if (i0 + r < n)
            ((float4*)lrow[r])[threadIdx.x] =
                ((const float4*)(embn + (size_t)(i0 + r) * D))[threadIdx.x];
    }
    if (threadIdx.x < DROWS) {
        const int ii = i0 + (int)threadIdx.x;
        la2[threadIdx.x] = (ii < n) ? a2[ii] : 0.f;
        lt[threadIdx.x] = (ii < n) ? t[ii] : -1;
    }
    __syncthreads();
    const int c = threadIdx.x;
    float best[DROWS];
    if (c < C) {
        float acc[DROWS];
#pragma unroll
        for (int r = 0; r < DROWS; ++r) acc[r] = 0.f;
        float c2acc = 0.f;
        const float4* cp = (const float4*)(centers + (size_t)c * D);
        for (int k = 0; k < D4; ++k) {
            const float4 cv = cp[k];
            c2acc += dot4(cv, cv);
#pragma unroll
            for (int r = 0; r < DROWS; ++r) {
                const float4 ev = ((const float4*)lrow[r])[k];
                acc[r] += cv.x * ev.x + cv.y * ev.y + cv.z * ev.z + cv.w * ev.w;
            }
        }
#pragma unroll
        for (int r = 0; r < DROWS; ++r) {
            const float sq = la2[r] + c2acc - 2.f * acc[r];
            float dv = sqrtf(fmaxf(sq, FEPS));
            if (lt[r] == c) dv = FBIG;
            best[r] = dv;
        }
    } else {
#pragma unroll
        for (int r = 0; r < DROWS; ++r) best[r] = FBIG;
    }
#pragma unroll
    for (int r = 0; r < DROWS; ++r) mins[r][threadIdx.x] = best[r];
    __syncthreads();
    for (int s = 64; s > 0; s >>= 1) {
        if (threadIdx.x < s) {
#pragma unroll
            for (int r = 0; r < DROWS; ++r)
                mins[r][threadIdx.x] = fminf(mins[r][threadIdx.x], mins[r][threadIdx.x + s]);
        }
        __syncthreads();
    }
    if (threadIdx.x < DROWS && i0 + (int)threadIdx.x < n)
        dneg[i0 + threadIdx.x] = mins[threadIdx.x][0];
}

// --- 5. per-class Gram tile + per-(row, j-tile) top-3 candidates ---
// grid (NIT*NJT, MAXC); 256 threads as 8(ty) x 32(tx); 4(i) x 2(j) register tile.
// Coalesced global staging + XOR-swizzled LDS (bank = row-dependent, so
// store [slot][row ^ slot]) + double buffer with ONE barrier per k-chunk.
__global__ __launch_bounds__(256) void k_pos(
    const float* __restrict__ embn, const float* __restrict__ a2,
    const int* __restrict__ clist, const int* __restrict__ coff,
    const int* __restrict__ ccount, float* __restrict__ candv,
    int* __restrict__ candj) {
    const int c = blockIdx.y;
    const int m = ccount[c];
    const int itile = blockIdx.x >> 1, jtile = blockIdx.x & 1;
    const int it0 = itile * TI, jt0 = jtile * TJ;
    if (m == 0 || it0 >= m) return;  // rows don't exist; nothing to write
    const int off = coff[c];
    const int tid = threadIdx.x;
    if (jt0 >= m) {  // j-tile empty: write sentinels so k_dpos merge is defined
        if (tid < TI && it0 + tid < m) {
            const int ig = clist[off + it0 + tid];
            const int base = ig * (NJT * 3) + jtile * 3;
            candj[base] = -1; candj[base + 1] = -1; candj[base + 2] = -1;
        }
        return;
    }

    const int tx = tid & 31;
    const int ty = tid >> 5;
    const int srow = tid >> 3;   // 0..31: global-load row group (coalesced by 8)
    const int sslot = tid & 7;   // 0..7: float4 slot within 32-float chunk

    __shared__ float4 At[2][8][TI];   // 8 KB  (XOR-swizzled rows)
    __shared__ float4 Bt[2][8][TJ];   // 16 KB
    __shared__ int ig_s[TI];
    __shared__ float a2i_s[TI];
    __shared__ int jg_s[TJ];
    __shared__ float a2j_s[TJ];

    if (tid < TI) {
        const int gr = it0 + tid;
        const int gi = (gr < m) ? clist[off + gr] : -1;
        ig_s[tid] = gi;
        a2i_s[tid] = (gi >= 0) ? a2[gi] : 0.f;
    } else if (tid >= 128 && tid < 128 + TJ) {
        const int q = tid - 128;
        const int gr = jt0 + q;
        const int gj = (gr < m) ? clist[off + gr] : -1;
        jg_s[q] = gj;
        a2j_s[q] = (gj >= 0) ? a2[gj] : 0.f;
    }
    __syncthreads();

    // loop-invariant row pointers (row 0 as dummy for padding; results unused)
    const int agi = ig_s[srow];
    const float4* gA = (const float4*)(embn + (size_t)((agi >= 0) ? agi : 0) * D);
    const int bg0 = jg_s[srow], bg1 = jg_s[srow + 32];
    const float4* gB0 = (const float4*)(embn + (size_t)((bg0 >= 0) ? bg0 : 0) * D);
    const float4* gB1 = (const float4*)(embn + (size_t)((bg1 >= 0) ? bg1 : 0) * D);

    float acc[4][2];
#pragma unroll
    for (int u = 0; u < 4; ++u) { acc[u][0] = 0.f; acc[u][1] = 0.f; }

    // prefetch chunk 0
    float4 pa = gA[sslot];
    float4 pb0 = gB0[sslot];
    float4 pb1 = gB1[sslot];

    for (int t = 0; t < 16; ++t) {
        const int cur = t & 1;
        // write prefetched chunk into buf[cur] (XOR-swizzled: bank = 4*sslot)
        At[cur][sslot][srow ^ sslot] = pa;
        Bt[cur][sslot][srow ^ sslot] = pb0;
        Bt[cur][sslot][(srow + 32) ^ sslot] = pb1;
        if (t < 15) {  // issue next chunk's loads; consumed after next barrier
            const int o = (t + 1) * 8 + sslot;
            pa = gA[o]; pb0 = gB0[o]; pb1 = gB1[o];
        }
        __syncthreads();  // buf[cur] visible; all waves done computing buf[cur^1]
#pragma unroll
        for (int k4 = 0; k4 < 8; ++k4) {
            const float4 b0 = Bt[cur][k4][tx ^ k4];
            const float4 b1 = Bt[cur][k4][(tx + 32) ^ k4];
#pragma unroll
            for (int u = 0; u < 4; ++u) {
                const float4 a = At[cur][k4][(ty + 8 * u) ^ k4];  // broadcast
                acc[u][0] += dot4(a, b0);
                acc[u][1] += dot4(a, b1);
            }
        }
    }

    // per-thread top3 per owned i-row over its 2 j's
    float rv0[4], rv1[4], rv2[4];
    int rj0[4], rj1[4], rj2[4];
#pragma unroll
    for (int u = 0; u < 4; ++u) {
        rv0[u] = rv1[u] = rv2[u] = -FBIG;
        rj0[u] = rj1[u] = rj2[u] = -1;
        const int iloc = ty + 8 * u;
        const int ig = ig_s[iloc];
        if (ig < 0) continue;
        const float a2i = a2i_s[iloc];
#pragma unroll
        for (int v = 0; v < 2; ++v) {
            const int jloc = tx + 32 * v;
            const int jg = jg_s[jloc];
            if (jg >= 0 && jg != ig) {
                const float sq = a2i + a2j_s[jloc] - 2.f * acc[u][v];
                ins3(sq, jg, rv0[u], rv1[u], rv2[u], rj0[u], rj1[u], rj2[u]);
            }
        }
    }

    // butterfly merge across the 32 tx lanes
#pragma unroll
    for (int o = 16; o > 0; o >>= 1) {
#pragma unroll
        for (int u = 0; u < 4; ++u) {
            const float ov0 = __shfl_xor(rv0[u], o); const int oj0 = __shfl_xor(rj0[u], o);
            const float ov1 = __shfl_xor(rv1[u], o); const int oj1 = __shfl_xor(rj1[u], o);
            const float ov2 = __shfl_xor(rv2[u], o); const int oj2 = __shfl_xor(rj2[u], o);
            ins3(ov0, oj0, rv0[u], rv1[u], rv2[u], rj0[u], rj1[u], rj2[u]);
            ins3(ov1, oj1, rv0[u], rv1[u], rv2[u], rj0[u], rj1[u], rj2[u]);
            ins3(ov2, oj2, rv0[u], rv1[u], rv2[u], rj0[u], rj1[u], rj2[u]);
        }
    }
    if (tx == 0) {
#pragma unroll
        for (int u = 0; u < 4; ++u) {
            const int iloc = ty + 8 * u;
            const int ig = ig_s[iloc];
            if (ig >= 0) {
                const int base = ig * (NJT * 3) + jtile * 3;
                candv[base] = rv0[u]; candv[base + 1] = rv1[u]; candv[base + 2] = rv2[u];
                candj[base] = rj0[u]; candj[base + 1] = rj1[u]; candj[base + 2] = rj2[u];
            }
        }
    }
}

// --- 6. fused: merge candidates -> d_pos -> softplus -> masked-mean reduce ---
// 256 threads = 4 waves, one row per wave. grid = n/4.
__global__ void k_dpos(const float* __restrict__ embn, const float* __restrict__ dneg,
                       const float* __restrict__ candv, const int* __restrict__ candj,
                       float* __restrict__ accum, int* __restrict__ done,
                       float* __restrict__ out, int n, int nblocks) {
    const int tid = threadIdx.x;
    const int wav = tid >> 6, lane = tid & 63;
    const int row = blockIdx.x * 4 + wav;
    float l = 0.f, vv = 0.f;
    float mv0 = -FBIG, mv1 = -FBIG, mv2 = -FBIG;
    int mj0 = -1, mj1 = -1, mj2 = -1;
#pragma unroll
    for (int s = 0; s < NJT * 3; ++s) {
        ins3(candv[row * (NJT * 3) + s], candj[row * (NJT * 3) + s],
             mv0, mv1, mv2, mj0, mj1, mj2);
    }
    const int nw = (mj0 >= 0) + (mj1 >= 0) + (mj2 >= 0);
    if (nw > 0) {
        const int jA = mj0;
        const int jB = (mj1 >= 0) ? mj1 : jA;
        const int jC = (mj2 >= 0) ? mj2 : jB;
        const float4* pi = (const float4*)(embn + (size_t)row * D);
        const float4* r0 = (const float4*)(embn + (size_t)jA * D);
        const float4* r1 = (const float4*)(embn + (size_t)jB * D);
        const float4* r2 = (const float4*)(embn + (size_t)jC * D);
        float accp = 0.f;
#pragma unroll
        for (int s = 0; s < 2; ++s) {
            const int k4 = lane + 64 * s;
            const float4 a = pi[k4];
            const float4 v0 = r0[k4], v1 = r1[k4], v2 = r2[k4];
            const float cx = (v0.x + v1.x + v2.x) * (1.f / 3.f);
            const float cy = (v0.y + v1.y + v2.y) * (1.f / 3.f);
            const float cz = (v0.z + v1.z + v2.z) * (1.f / 3.f);
            const float cw = (v0.w + v1.w + v2.w) * (1.f / 3.f);
            const float dx = a.x - cx, dy = a.y - cy, dz = a.z - cz, dw = a.w - cw;
            accp += dx * dx + dy * dy + dz * dz + dw * dw;
        }
        accp = wave_rsum_all(accp);
        const float dp = sqrtf(fmaxf(accp, FEPS));
        const float x = dp - dneg[row];
        l = fmaxf(x, 0.f) + log1pf(expf(-fabsf(x)));
        vv = 1.f;
    }
    __shared__ float wl[4], wv[4];
    if (lane == 0) { wl[wav] = l; wv[wav] = vv; }
    __syncthreads();
    if (tid == 0) {
        atomicAdd(&accum[0], wl[0] + wl[1] + wl[2] + wl[3]);
        atomicAdd(&accum[1], wv[0] + wv[1] + wv[2] + wv[3]);
        __threadfence();
        const int prev = atomicAdd(done, 1);
        if (prev == nblocks - 1) {
            __threadfence();
            const float sl = atomicAdd(&accum[0], 0.0f);  // coherent-point read
            const float sv = atomicAdd(&accum[1], 0.0f);
            out[0] = sl / fmaxf(sv, 1.0f);
        }
    }
}

extern "C" void kernel_launch(void* const* d_in, const int* in_sizes, int n_in,
                              void* d_out, int out_size, void* d_ws, size_t ws_size,
                              hipStream_t stream) {
    const float* emb = (const float*)d_in[0];
    const int* targets = (const int*)d_in[1];
    const int* ncls = (const int*)d_in[2];
    const int n = in_sizes[1];  // 8192

    float* fp = (float*)d_ws;
    float* embn = fp;    fp += (size_t)n * D;
    float* a2 = fp;      fp += n;
    float* centers = fp; fp += (size_t)MAXC * D;
    float* dneg = fp;    fp += n;
    float* candv = fp;   fp += (size_t)n * NJT * 3;
    int* candj = (int*)fp; fp += (size_t)n * NJT * 3;
    int* ccount = (int*)fp; fp += MAXC;
    float* accum = fp;   fp += 2;          // contiguous with ccount: one memset
    int* done = (int*)fp; fp += 1;
    int* coff = (int*)fp;   fp += MAXC;
    int* clist = (int*)fp;  fp += n;

    hipMemsetAsync(ccount, 0, (MAXC + 3) * sizeof(int), stream);

    const int ndp = n / 4;
    k_normalize<<<n, 128, 0, stream>>>(emb, targets, embn, a2, ccount);
    k_build<<<MAXC, 256, 0, stream>>>(targets, ccount, coff, clist, n, ncls);
    k_centers<<<dim3(4, MAXC), 128, 0, stream>>>(embn, clist, coff, ccount, centers);
    k_dneg<<<(n + DROWS - 1) / DROWS, 128, 0, stream>>>(embn, a2, targets, centers, dneg, n, ncls);
    k_pos<<<dim3(NIT * NJT, MAXC), 256, 0, stream>>>(embn, a2, clist, coff, ccount, candv, candj);
    k_dpos<<<ndp, 256, 0, stream>>>(embn, dneg, candv, candj, accum, done, (float*)d_out, n, ndp);
}

// Round 9
// 314.848 us; speedup vs baseline: 1.0287x; 1.0287x over previous
//
#include <hip/hip_runtime.h>

#define D 512
#define D4 (D / 4)
#define MAXC 256
#define FEPS 1e-12f
#define FBIG 3.0e38f
#define DROWS 8
#define TI 16    // i-rows per k_pos wave-block
#define TJ 32    // j-cols per k_pos wave-block
#define NIT 8    // i-tiles (covers class counts up to 128)
#define NJT 4    // j-tiles (covers class counts up to 128)

__device__ __forceinline__ float wave_rsum(float v) {
#pragma unroll
    for (int o = 32; o > 0; o >>= 1) v += __shfl_down(v, o);
    return v;
}

__device__ __forceinline__ float wave_rsum_all(float v) {
#pragma unroll
    for (int o = 32; o > 0; o >>= 1) v += __shfl_xor(v, o);
    return v;
}

__device__ __forceinline__ float dot4(const float4 a, const float4 b) {
    return a.x * b.x + a.y * b.y + a.z * b.z + a.w * b.w;
}

// top_k tie-break: higher value wins; equal values -> smaller global index wins
__device__ __forceinline__ bool better(float v1, int j1, float v2, int j2) {
    return (v1 > v2) || (v1 == v2 && (unsigned)j1 < (unsigned)j2);
}

__device__ __forceinline__ void ins3(float v, int j, float& t0, float& t1, float& t2,
                                     int& x0, int& x1, int& x2) {
    if (j < 0) return;
    if (better(v, j, t0, x0)) { t2 = t1; x2 = x1; t1 = t0; x1 = x0; t0 = v; x0 = j; }
    else if (better(v, j, t1, x1)) { t2 = t1; x2 = x1; t1 = v; x1 = j; }
    else if (better(v, j, t2, x2)) { t2 = v; x2 = j; }
}

// --- 1. row L2-normalize + a2[i] + fused class histogram ---
__global__ void k_normalize(const float* __restrict__ emb, const int* __restrict__ targets,
                            float* __restrict__ embn, float* __restrict__ a2,
                            int* __restrict__ ccount) {
    const int i = blockIdx.x;
    const int tid = threadIdx.x;  // 128 threads, float4 each
    __shared__ float red[2];
    const float4 x = ((const float4*)(emb + (size_t)i * D))[tid];
    float ss = x.x * x.x + x.y * x.y + x.z * x.z + x.w * x.w;
    ss = wave_rsum(ss);
    if ((tid & 63) == 0) red[tid >> 6] = ss;
    __syncthreads();
    const float tot = red[0] + red[1];
    const float inv = 1.0f / fmaxf(sqrtf(tot), FEPS);
    const float4 y = make_float4(x.x * inv, x.y * inv, x.z * inv, x.w * inv);
    ((float4*)(embn + (size_t)i * D))[tid] = y;
    float s2 = y.x * y.x + y.y * y.y + y.z * y.z + y.w * y.w;
    s2 = wave_rsum(s2);
    __syncthreads();
    if ((tid & 63) == 0) red[tid >> 6] = s2;
    __syncthreads();
    if (tid == 0) {
        a2[i] = red[0] + red[1];
        atomicAdd(&ccount[targets[i]], 1);
    }
}

// --- 2. per-class offset (in-block prefix reduce) + deterministic row lists ---
__global__ void k_build(const int* __restrict__ t, const int* __restrict__ ccount,
                        int* __restrict__ coff, int* __restrict__ clist, int n,
                        const int* __restrict__ ncls) {
    const int C = *ncls;
    const int c = blockIdx.x;  // grid = MAXC
    if (c >= C) return;
    __shared__ int pref[256];
    pref[threadIdx.x] = ((int)threadIdx.x < c) ? ccount[threadIdx.x] : 0;
    __syncthreads();
    for (int s = 128; s > 0; s >>= 1) {
        if (threadIdx.x < s) pref[threadIdx.x] += pref[threadIdx.x + s];
        __syncthreads();
    }
    int base = pref[0];
    if (threadIdx.x == 0) coff[c] = base;
    __shared__ int wtot[4];
    for (int start = 0; start < n; start += 256) {
        const int j = start + (int)threadIdx.x;
        const bool flag = (j < n) && (t[j] == c);
        const unsigned long long m = __ballot(flag);
        const int lane = threadIdx.x & 63;
        const int w = threadIdx.x >> 6;
        const int pre = __popcll(m & ((1ull << lane) - 1ull));
        if (lane == 0) wtot[w] = __popcll(m);
        __syncthreads();
        int woff = 0;
        for (int k = 0; k < w; ++k) woff += wtot[k];
        const int tot = wtot[0] + wtot[1] + wtot[2] + wtot[3];
        if (flag) clist[base + woff + pre] = j;
        base += tot;
        __syncthreads();
    }
}

// --- 3. class centers: grid (4 d-chunks x MAXC), 128 threads ---
__global__ void k_centers(const float* __restrict__ embn, const int* __restrict__ clist,
                          const int* __restrict__ coff, const int* __restrict__ ccount,
                          float* __restrict__ centers) {
    const int c = blockIdx.y;
    const int dchunk = blockIdx.x;      // 32 float4 slots each
    const int cnt = ccount[c];
    const int off = (cnt > 0) ? coff[c] : 0;
    const int tid = threadIdx.x;        // 128
    const int slot = tid & 31;
    const int rg = tid >> 5;            // 0..3
    float4 s = make_float4(0.f, 0.f, 0.f, 0.f);
    for (int mi = rg; mi < cnt; mi += 4) {
        const int j = clist[off + mi];
        const float4 e = ((const float4*)(embn + (size_t)j * D))[dchunk * 32 + slot];
        s.x += e.x; s.y += e.y; s.z += e.z; s.w += e.w;
    }
    __shared__ float4 part[4][32];
    part[rg][slot] = s;
    __syncthreads();
    if (rg == 0) {
        const float4 p0 = part[0][slot], p1 = part[1][slot], p2 = part[2][slot], p3 = part[3][slot];
        const float inv = 1.0f / fmaxf((float)cnt, 1e-6f);
        const float4 v = make_float4((p0.x + p1.x + p2.x + p3.x) * inv,
                                     (p0.y + p1.y + p2.y + p3.y) * inv,
                                     (p0.z + p1.z + p2.z + p3.z) * inv,
                                     (p0.w + p1.w + p2.w + p3.w) * inv);
        ((float4*)(centers + (size_t)c * D))[dchunk * 32 + slot] = v;
    }
}

// --- 4. d_neg_min: 8 rows per block, one thread per class (cc2 inline) ---
__global__ void k_dneg(const float* __restrict__ embn, const float* __restrict__ a2,
                       const int* __restrict__ t, const float* __restrict__ centers,
                       float* __restrict__ dneg, int n, const int* __restrict__ ncls) {
    const int C = *ncls;
    const int i0 = blockIdx.x * DROWS;
    __shared__ __align__(16) float lrow[DROWS][D];
    __shared__ float la2[DROWS];
    __shared__ int lt[DROWS];
    __shared__ float mins[DROWS][128];
#pragma unroll
    for (int r = 0; r < DROWS; ++r) {
        if (i0 + r < n)
            ((float4*)lrow[r])[threadIdx.x] =
                ((const float4*)(embn + (size_t)(i0 + r) * D))[threadIdx.x];
    }
    if (threadIdx.x < DROWS) {
        const int ii = i0 + (int)threadIdx.x;
        la2[threadIdx.x] = (ii < n) ? a2[ii] : 0.f;
        lt[threadIdx.x] = (ii < n) ? t[ii] : -1;
    }
    __syncthreads();
    const int c = threadIdx.x;
    float best[DROWS];
    if (c < C) {
        float acc[DROWS];
#pragma unroll
        for (int r = 0; r < DROWS; ++r) acc[r] = 0.f;
        float c2acc = 0.f;
        const float4* cp = (const float4*)(centers + (size_t)c * D);
        for (int k = 0; k < D4; ++k) {
            const float4 cv = cp[k];
            c2acc += dot4(cv, cv);
#pragma unroll
            for (int r = 0; r < DROWS; ++r) {
                const float4 ev = ((const float4*)lrow[r])[k];
                acc[r] += cv.x * ev.x + cv.y * ev.y + cv.z * ev.z + cv.w * ev.w;
            }
        }
#pragma unroll
        for (int r = 0; r < DROWS; ++r) {
            const float sq = la2[r] + c2acc - 2.f * acc[r];
            float dv = sqrtf(fmaxf(sq, FEPS));
            if (lt[r] == c) dv = FBIG;
            best[r] = dv;
        }
    } else {
#pragma unroll
        for (int r = 0; r < DROWS; ++r) best[r] = FBIG;
    }
#pragma unroll
    for (int r = 0; r < DROWS; ++r) mins[r][threadIdx.x] = best[r];
    __syncthreads();
    for (int s = 64; s > 0; s >>= 1) {
        if (threadIdx.x < s) {
#pragma unroll
            for (int r = 0; r < DROWS; ++r)
                mins[r][threadIdx.x] = fminf(mins[r][threadIdx.x], mins[r][threadIdx.x + s]);
        }
        __syncthreads();
    }
    if (threadIdx.x < DROWS && i0 + (int)threadIdx.x < n)
        dneg[i0 + threadIdx.x] = mins[threadIdx.x][0];
}

// --- 5. per-class Gram tile: SINGLE-WAVE blocks, NO barriers ---
// grid (NIT*NJT, MAXC); 64 threads = 16(tx) x 4(ty); 4(i) x 2(j) register tile
// over a 16x32 tile. LDS staging is wave-private: ds ops are program-ordered
// within a wave, so no __syncthreads -> no vmcnt(0) drain -> prefetch loads
// genuinely overlap compute. XOR-swizzled LDS (bank = 4*slot on writes).
__global__ __launch_bounds__(64) void k_pos(
    const float* __restrict__ embn, const float* __restrict__ a2,
    const int* __restrict__ clist, const int* __restrict__ coff,
    const int* __restrict__ ccount, float* __restrict__ candv,
    int* __restrict__ candj) {
    const int c = blockIdx.y;
    const int m = ccount[c];
    const int itile = blockIdx.x >> 2, jtile = blockIdx.x & 3;
    const int it0 = itile * TI, jt0 = jtile * TJ;
    if (m == 0 || it0 >= m) return;  // rows don't exist; nothing to write
    const int off = coff[c];
    const int lane = threadIdx.x;  // 0..63
    if (jt0 >= m) {  // empty j-tile: write sentinels so the merge is defined
        if (lane < TI && it0 + lane < m) {
            const int ig = clist[off + it0 + lane];
            const int base = ig * (NJT * 3) + jtile * 3;
            candj[base] = -1; candj[base + 1] = -1; candj[base + 2] = -1;
        }
        return;
    }

    const int tx = lane & 15;
    const int ty = lane >> 4;     // 0..3
    const int ar = lane >> 3;     // staging row group 0..7
    const int slot = lane & 7;    // float4 slot within 32-float chunk

    __shared__ float4 At[2][8][TI];   // 4 KB (XOR-swizzled rows)
    __shared__ float4 Bt[2][8][TJ];   // 8 KB
    __shared__ int ig_s[TI];
    __shared__ float a2i_s[TI];
    __shared__ int jg_s[TJ];
    __shared__ float a2j_s[TJ];

    if (lane < TI) {
        const int gr = it0 + lane;
        const int gi = (gr < m) ? clist[off + gr] : -1;
        ig_s[lane] = gi;
        a2i_s[lane] = (gi >= 0) ? a2[gi] : 0.f;
    } else if (lane < TI + TJ) {
        const int q = lane - TI;
        const int gr = jt0 + q;
        const int gj = (gr < m) ? clist[off + gr] : -1;
        jg_s[q] = gj;
        a2j_s[q] = (gj >= 0) ? a2[gj] : 0.f;
    }

    // per-thread global staging pointers (row 0 as dummy for padding)
    const int ra0 = it0 + ar, ra1 = it0 + ar + 8;
    const float4* gA0 = (const float4*)(embn + (size_t)((ra0 < m) ? clist[off + ra0] : 0) * D);
    const float4* gA1 = (const float4*)(embn + (size_t)((ra1 < m) ? clist[off + ra1] : 0) * D);
    const int rb0 = jt0 + ar, rb1 = rb0 + 8, rb2 = rb0 + 16, rb3 = rb0 + 24;
    const float4* gB0 = (const float4*)(embn + (size_t)((rb0 < m) ? clist[off + rb0] : 0) * D);
    const float4* gB1 = (const float4*)(embn + (size_t)((rb1 < m) ? clist[off + rb1] : 0) * D);
    const float4* gB2 = (const float4*)(embn + (size_t)((rb2 < m) ? clist[off + rb2] : 0) * D);
    const float4* gB3 = (const float4*)(embn + (size_t)((rb3 < m) ? clist[off + rb3] : 0) * D);

    float acc[4][2];
#pragma unroll
    for (int u = 0; u < 4; ++u) { acc[u][0] = 0.f; acc[u][1] = 0.f; }

    // prefetch chunk 0
    float4 pa0 = gA0[slot], pa1 = gA1[slot];
    float4 pb0 = gB0[slot], pb1 = gB1[slot], pb2 = gB2[slot], pb3 = gB3[slot];

    for (int t = 0; t < 16; ++t) {
        const int cur = t & 1;
        // write prefetched chunk (swizzled: write bank = 4*slot, conflict-free)
        At[cur][slot][ar ^ slot] = pa0;
        At[cur][slot][(ar + 8) ^ slot] = pa1;
        Bt[cur][slot][ar ^ slot] = pb0;
        Bt[cur][slot][(ar + 8) ^ slot] = pb1;
        Bt[cur][slot][(ar + 16) ^ slot] = pb2;
        Bt[cur][slot][(ar + 24) ^ slot] = pb3;
        if (t < 15) {  // issue next chunk's loads; they fly under this compute
            const int o = (t + 1) * 8 + slot;
            pa0 = gA0[o]; pa1 = gA1[o];
            pb0 = gB0[o]; pb1 = gB1[o]; pb2 = gB2[o]; pb3 = gB3[o];
        }
#pragma unroll
        for (int k4 = 0; k4 < 8; ++k4) {
            const float4 b0 = Bt[cur][k4][tx ^ k4];
            const float4 b1 = Bt[cur][k4][(tx + 16) ^ k4];
#pragma unroll
            for (int u = 0; u < 4; ++u) {
                const float4 a = At[cur][k4][(ty + 4 * u) ^ k4];  // broadcast
                acc[u][0] += dot4(a, b0);
                acc[u][1] += dot4(a, b1);
            }
        }
    }

    // per-thread top3 per owned i-row over its 2 j's
    float rv0[4], rv1[4], rv2[4];
    int rj0[4], rj1[4], rj2[4];
#pragma unroll
    for (int u = 0; u < 4; ++u) {
        rv0[u] = rv1[u] = rv2[u] = -FBIG;
        rj0[u] = rj1[u] = rj2[u] = -1;
        const int iloc = ty + 4 * u;
        const int ig = ig_s[iloc];
        if (ig < 0) continue;
        const float a2i = a2i_s[iloc];
#pragma unroll
        for (int v = 0; v < 2; ++v) {
            const int jloc = tx + 16 * v;
            const int jg = jg_s[jloc];
            if (jg >= 0 && jg != ig) {
                const float sq = a2i + a2j_s[jloc] - 2.f * acc[u][v];
                ins3(sq, jg, rv0[u], rv1[u], rv2[u], rj0[u], rj1[u], rj2[u]);
            }
        }
    }

    // butterfly merge across the 16 tx lanes (lane xor stays within ty group)
#pragma unroll
    for (int o = 8; o > 0; o >>= 1) {
#pragma unroll
        for (int u = 0; u < 4; ++u) {
            const float ov0 = __shfl_xor(rv0[u], o); const int oj0 = __shfl_xor(rj0[u], o);
            const float ov1 = __shfl_xor(rv1[u], o); const int oj1 = __shfl_xor(rj1[u], o);
            const float ov2 = __shfl_xor(rv2[u], o); const int oj2 = __shfl_xor(rj2[u], o);
            ins3(ov0, oj0, rv0[u], rv1[u], rv2[u], rj0[u], rj1[u], rj2[u]);
            ins3(ov1, oj1, rv0[u], rv1[u], rv2[u], rj0[u], rj1[u], rj2[u]);
            ins3(ov2, oj2, rv0[u], rv1[u], rv2[u], rj0[u], rj1[u], rj2[u]);
        }
    }
    if (tx == 0) {
#pragma unroll
        for (int u = 0; u < 4; ++u) {
            const int iloc = ty + 4 * u;
            const int ig = ig_s[iloc];
            if (ig >= 0) {
                const int base = ig * (NJT * 3) + jtile * 3;
                candv[base] = rv0[u]; candv[base + 1] = rv1[u]; candv[base + 2] = rv2[u];
                candj[base] = rj0[u]; candj[base + 1] = rj1[u]; candj[base + 2] = rj2[u];
            }
        }
    }
}

// --- 6. fused: merge candidates -> d_pos -> softplus -> masked-mean reduce ---
// 256 threads = 4 waves, one row per wave. grid = n/4.
__global__ void k_dpos(const float* __restrict__ embn, const float* __restrict__ dneg,
                       const float* __restrict__ candv, const int* __restrict__ candj,
                       float* __restrict__ accum, int* __restrict__ done,
                       float* __restrict__ out, int n, int nblocks) {
    const int tid = threadIdx.x;
    const int wav = tid >> 6, lane = tid & 63;
    const int row = blockIdx.x * 4 + wav;
    float l = 0.f, vv = 0.f;
    float mv0 = -FBIG, mv1 = -FBIG, mv2 = -FBIG;
    int mj0 = -1, mj1 = -1, mj2 = -1;
#pragma unroll
    for (int s = 0; s < NJT * 3; ++s) {
        ins3(candv[row * (NJT * 3) + s], candj[row * (NJT * 3) + s],
             mv0, mv1, mv2, mj0, mj1, mj2);
    }
    const int nw = (mj0 >= 0) + (mj1 >= 0) + (mj2 >= 0);
    if (nw > 0) {
        const int jA = mj0;
        const int jB = (mj1 >= 0) ? mj1 : jA;
        const int jC = (mj2 >= 0) ? mj2 : jB;
        const float4* pi = (const float4*)(embn + (size_t)row * D);
        const float4* r0 = (const float4*)(embn + (size_t)jA * D);
        const float4* r1 = (const float4*)(embn + (size_t)jB * D);
        const float4* r2 = (const float4*)(embn + (size_t)jC * D);
        float accp = 0.f;
#pragma unroll
        for (int s = 0; s < 2; ++s) {
            const int k4 = lane + 64 * s;
            const float4 a = pi[k4];
            const float4 v0 = r0[k4], v1 = r1[k4], v2 = r2[k4];
            const float cx = (v0.x + v1.x + v2.x) * (1.f / 3.f);
            const float cy = (v0.y + v1.y + v2.y) * (1.f / 3.f);
            const float cz = (v0.z + v1.z + v2.z) * (1.f / 3.f);
            const float cw = (v0.w + v1.w + v2.w) * (1.f / 3.f);
            const float dx = a.x - cx, dy = a.y - cy, dz = a.z - cz, dw = a.w - cw;
            accp += dx * dx + dy * dy + dz * dz + dw * dw;
        }
        accp = wave_rsum_all(accp);
        const float dp = sqrtf(fmaxf(accp, FEPS));
        const float x = dp - dneg[row];
        l = fmaxf(x, 0.f) + log1pf(expf(-fabsf(x)));
        vv = 1.f;
    }
    __shared__ float wl[4], wv[4];
    if (lane == 0) { wl[wav] = l; wv[wav] = vv; }
    __syncthreads();
    if (tid == 0) {
        atomicAdd(&accum[0], wl[0] + wl[1] + wl[2] + wl[3]);
        atomicAdd(&accum[1], wv[0] + wv[1] + wv[2] + wv[3]);
        __threadfence();
        const int prev = atomicAdd(done, 1);
        if (prev == nblocks - 1) {
            __threadfence();
            const float sl = atomicAdd(&accum[0], 0.0f);  // coherent-point read
            const float sv = atomicAdd(&accum[1], 0.0f);
            out[0] = sl / fmaxf(sv, 1.0f);
        }
    }
}

extern "C" void kernel_launch(void* const* d_in, const int* in_sizes, int n_in,
                              void* d_out, int out_size, void* d_ws, size_t ws_size,
                              hipStream_t stream) {
    const float* emb = (const float*)d_in[0];
    const int* targets = (const int*)d_in[1];
    const int* ncls = (const int*)d_in[2];
    const int n = in_sizes[1];  // 8192

    float* fp = (float*)d_ws;
    float* embn = fp;    fp += (size_t)n * D;
    float* a2 = fp;      fp += n;
    float* centers = fp; fp += (size_t)MAXC * D;
    float* dneg = fp;    fp += n;
    float* candv = fp;   fp += (size_t)n * NJT * 3;
    int* candj = (int*)fp; fp += (size_t)n * NJT * 3;
    int* ccount = (int*)fp; fp += MAXC;
    float* accum = fp;   fp += 2;          // contiguous with ccount: one memset
    int* done = (int*)fp; fp += 1;
    int* coff = (int*)fp;   fp += MAXC;
    int* clist = (int*)fp;  fp += n;

    hipMemsetAsync(ccount, 0, (MAXC + 3) * sizeof(int), stream);

    const int ndp = n / 4;
    k_normalize<<<n, 128, 0, stream>>>(emb, targets, embn, a2, ccount);
    k_build<<<MAXC, 256, 0, stream>>>(targets, ccount, coff, clist, n, ncls);
    k_centers<<<dim3(4, MAXC), 128, 0, stream>>>(embn, clist, coff, ccount, centers);
    k_dneg<<<(n + DROWS - 1) / DROWS, 128, 0, stream>>>(embn, a2, targets, centers, dneg, n, ncls);
    k_pos<<<dim3(NIT * NJT, MAXC), 64, 0, stream>>>(embn, a2, clist, coff, ccount, candv, candj);
    k_dpos<<<ndp, 256, 0, stream>>>(embn, dneg, candv, candj, accum, done, (float*)d_out, n, ndp);
}